// Round 5
// baseline (156.075 us; speedup 1.0000x reference)
//
#include <hip/hip_runtime.h>
#include <hip/hip_bf16.h>
#include <cstddef>

#define DIMC   768
#define HEADS  12
#define BATCH  4
#define SEQ    2048
#define MROWS  (BATCH * SEQ)      // 8192
#define NCAT   1920               // Wtcat rows: 1152 (head-major [Wa|Wb]) + 768 (Wv)
#define NAB    1152

typedef unsigned short u16;
typedef __attribute__((ext_vector_type(8))) short short8;   // 8 bf16 = 4 VGPRs
typedef __attribute__((ext_vector_type(4))) float floatx4;  // MFMA C/D

__device__ inline u16 f2bf(float f) {
    union { float f; unsigned u; } v; v.f = f;
    unsigned u = v.u + 0x7FFF + ((v.u >> 16) & 1);   // RNE
    return (u16)(u >> 16);
}
__device__ inline float bf2f(u16 h) {
    union { unsigned u; float f; } v; v.u = ((unsigned)h) << 16;
    return v.f;
}

// async 16B/lane global->LDS; lane i lands at lptr + i*16 (wave-uniform base)
__device__ inline void async_load16(const void* g, void* l) {
    __builtin_amdgcn_global_load_lds(
        (const __attribute__((address_space(1))) void*)g,
        (__attribute__((address_space(3))) void*)l, 16, 0, 0);
}

// ---------------------------------------------------------------------------
// Fused prep (unchanged):
//  [0,3072)      x fp32 -> xb bf16 (8 elem/thread)
//  [3072,3432)   Wtcat 64x64 tile-transpose from [Wa|Wb|Wv]
//                ab rows HEAD-MAJOR: head h rows [h*96,h*96+96) =
//                64 Wa cols (h*64..) then 32 Wb cols (h*32..)
//  [3432,3576)   Wpt from Wp
//  [3576,3832)   xs-pool: xs[p][c] = sum_{j<32} x[(p*32+j)*768 + c] (bf16)
// ---------------------------------------------------------------------------
__global__ __launch_bounds__(256)
void prep_kernel(const float* __restrict__ x,
                 const float* __restrict__ Wa, const float* __restrict__ Wb,
                 const float* __restrict__ Wv, const float* __restrict__ Wp,
                 u16* __restrict__ xb, u16* __restrict__ Wtcat,
                 u16* __restrict__ Wpt, u16* __restrict__ xs)
{
    const int tid = threadIdx.x;
    const int bidg = blockIdx.x;
    if (bidg < 3072) {
        int i = bidg * 256 + tid;
        const float4 f0 = ((const float4*)x)[(size_t)i * 2];
        const float4 f1 = ((const float4*)x)[(size_t)i * 2 + 1];
        u16 tmp[8] = { f2bf(f0.x), f2bf(f0.y), f2bf(f0.z), f2bf(f0.w),
                       f2bf(f1.x), f2bf(f1.y), f2bf(f1.z), f2bf(f1.w) };
        *(uint4*)&xb[(size_t)i * 8] = *(uint4*)tmp;
        return;
    }
    if (bidg >= 3576) {
        const int p = bidg - 3576;                 // [0,256)
#pragma unroll
        for (int k = 0; k < 3; ++k) {
            const int c = k * 256 + tid;
            const float* src = x + (size_t)p * 32 * DIMC + c;
            float s = 0.f;
#pragma unroll
            for (int j = 0; j < 32; ++j) s += src[(size_t)j * DIMC];
            xs[(size_t)p * DIMC + c] = f2bf(s);
        }
        return;
    }
    __shared__ u16 tile[64 * 72];
    int bid = bidg - 3072;
    const float* src; u16* dst; int n0, k0, ld, col0;
    bool remap = false;
    if (bid < 360) {
        int nt = bid / 12, kt = bid % 12;
        n0 = nt * 64; k0 = kt * 64; dst = Wtcat;
        if (n0 < 768)       { src = Wa; ld = 768; col0 = n0; remap = true; }
        else if (n0 < 1152) { src = Wb; ld = 384; col0 = n0 - 768; remap = true; }
        else                { src = Wv; ld = 768; col0 = n0 - 1152; }
    } else {
        int b2 = bid - 360;
        int nt = b2 / 12, kt = b2 % 12;
        n0 = nt * 64; k0 = kt * 64; dst = Wpt; src = Wp; ld = 768; col0 = n0;
    }
#pragma unroll
    for (int p = 0; p < 16; ++p) {
        int i = p * 256 + tid;
        int k = i >> 6, n = i & 63;
        tile[n * 72 + k] = f2bf(src[(size_t)(k0 + k) * ld + col0 + n]);
    }
    __syncthreads();
    int n = tid >> 2, kc = (tid & 3) * 16;
    int orow = n0 + n;
    int drow = orow;
    if (remap) {
        if (orow < 768) drow = (orow >> 6) * 96 + (orow & 63);              // Wa
        else { int c = orow - 768; drow = (c >> 5) * 96 + 64 + (c & 31); }  // Wb
    }
    uint4 o0 = *(uint4*)&tile[n * 72 + kc];
    uint4 o1 = *(uint4*)&tile[n * 72 + kc + 8];
    *(uint4*)&dst[(size_t)drow * DIMC + k0 + kc] = o0;
    *(uint4*)&dst[(size_t)drow * DIMC + k0 + kc + 8] = o1;
}

// ---------------------------------------------------------------------------
// gemm2 — RETILED 64x128 for grid balance (round-4-proven geometry).
// Grid (8192/64, 768/128) = 128x6 = 768 blocks = 3.0/CU.
// 4 waves; wave owns 32x64 (wm=(w&1)*32, wn=(w>>1)*64); acc[2][4] = 32 VGPR.
// Staging 3 loads/thread/K-step (1 A + 2 B), dbuf, vmcnt(3), wrap staging —
// same validated discipline; accumulation order identical to old kernel.
// ---------------------------------------------------------------------------
template<bool WRITE_BF16>
__global__ __launch_bounds__(256, 3)
void gemm_bf16_kernel(const u16* __restrict__ A, const u16* __restrict__ Bt,
                      const float* __restrict__ bias, void* __restrict__ Cout,
                      int K, int ldC)
{
    __shared__ u16 As[2][2048];   // 64 x 32
    __shared__ u16 Bs[2][4096];   // 128 x 32

    const int tid  = threadIdx.x;
    const int lane = tid & 63, wave = tid >> 6;
    const int quad = lane >> 4, l16 = lane & 15;
    const int wm = (wave & 1) * 32, wn = (wave >> 1) * 64;
    const int m0 = blockIdx.x * 64, n0 = blockIdx.y * 128;

    const int lrow = lane >> 2, lchunk = lane & 3;
    const u16* gA = A  + (size_t)(m0 + wave * 16 + lrow) * K + lchunk * 8;
    const u16* gB = Bt + (size_t)(n0 + wave * 32 + lrow) * K + lchunk * 8;
    const int NT = K / 32;   // 24

#define STAGE(buf, kt_) do {                                                  \
        const int _k0 = (kt_) * 32;                                           \
        async_load16(gA + _k0,          &As[buf][wave * 512]);                \
        async_load16(gB + _k0,          &Bs[buf][wave * 1024]);               \
        async_load16(gB + _k0 + 16 * K, &Bs[buf][wave * 1024 + 512]);         \
    } while (0)

#define COMPUTE(buf) do {                                                     \
        short8 af[2], bf[4];                                                  \
        _Pragma("unroll")                                                     \
        for (int t = 0; t < 2; ++t)                                           \
            af[t] = *(short8*)&As[buf][(wm + t * 16 + l16) * 32 + quad * 8];  \
        _Pragma("unroll")                                                     \
        for (int t = 0; t < 4; ++t)                                           \
            bf[t] = *(short8*)&Bs[buf][(wn + t * 16 + l16) * 32 + quad * 8];  \
        _Pragma("unroll")                                                     \
        for (int mt = 0; mt < 2; ++mt)                                        \
            _Pragma("unroll")                                                 \
            for (int nt = 0; nt < 4; ++nt)                                    \
                acc[mt][nt] = __builtin_amdgcn_mfma_f32_16x16x32_bf16(        \
                    af[mt], bf[nt], acc[mt][nt], 0, 0, 0);                    \
    } while (0)

    floatx4 acc[2][4] = {};
    STAGE(0, 0);
    STAGE(1, 1);
#pragma unroll 2
    for (int kt = 0; kt < NT; ++kt) {
        const int buf = kt & 1;
        __asm__ volatile("s_waitcnt vmcnt(3)" ::: "memory");  // retire older 3
        __asm__ volatile("s_barrier" ::: "memory");
        COMPUTE(buf);
        __asm__ volatile("s_barrier" ::: "memory");
        STAGE(buf, (kt + 2) % NT);
    }
#undef STAGE
#undef COMPUTE

#pragma unroll
    for (int mt = 0; mt < 2; ++mt)
#pragma unroll
        for (int nt = 0; nt < 4; ++nt) {
            const int gc = n0 + wn + nt * 16 + l16;
            const float bv = bias ? bias[gc] : 0.f;
#pragma unroll
            for (int r = 0; r < 4; ++r) {
                const int gr = m0 + wm + mt * 16 + quad * 4 + r;
                const float v = acc[mt][nt][r] + bv;
                if (WRITE_BF16) ((u16*)Cout)[(size_t)gr * ldC + gc] = f2bf(v);
                else            ((float*)Cout)[(size_t)gr * ldC + gc] = v;
            }
        }
}

// ---------------------------------------------------------------------------
// Vs kernel — unchanged (validated). VsT[bh][d][t] bf16.
// ---------------------------------------------------------------------------
__global__ __launch_bounds__(256)
void vs_kernel(const u16* __restrict__ xs, const u16* __restrict__ Wvt,
               u16* __restrict__ VsT)
{
    const int tid = threadIdx.x;
    const int lane = tid & 63, wave = tid >> 6;
    const int quad = lane >> 4, l16 = lane & 15;
    const int bh = blockIdx.x;
    const int b = bh / HEADS, h = bh % HEADS;
    const int K = DIMC;

    const u16* gA = Wvt + (size_t)(h * 64 + wave * 16 + l16) * K + quad * 8;
    const u16* gB = xs  + (size_t)(b * 64 + l16) * K + quad * 8;

    floatx4 acc[4] = {};
    for (int it = 0; it < 24; ++it) {
        short8 af = *(const short8*)(gA + it * 32);
        short8 bf[4];
#pragma unroll
        for (int nt = 0; nt < 4; ++nt)
            bf[nt] = *(const short8*)(gB + (size_t)nt * 16 * K + it * 32);
#pragma unroll
        for (int nt = 0; nt < 4; ++nt)
            acc[nt] = __builtin_amdgcn_mfma_f32_16x16x32_bf16(
                af, bf[nt], acc[nt], 0, 0, 0);
    }
#pragma unroll
    for (int nt = 0; nt < 4; ++nt)
#pragma unroll
        for (int r = 0; r < 4; ++r) {
            const int d = wave * 16 + quad * 4 + r;
            const int t = nt * 16 + l16;
            VsT[(size_t)bh * 4096 + d * 64 + t] = f2bf(acc[nt][r]);
        }
}

// ---------------------------------------------------------------------------
// FUSED gemm1 + attention, 64x192 (round-4 validated). 4 waves; wave w owns
// rows (w&1)*32, head (w>>1). acc[2][6]; 3 blocks/CU; vmcnt(4) dbuf.
// ---------------------------------------------------------------------------
__global__ __launch_bounds__(256, 3)
void gemm1_attn_kernel(const u16* __restrict__ xb, const u16* __restrict__ Wab,
                       const u16* __restrict__ VsT, u16* __restrict__ Hb)
{
    __shared__ u16 smem[16384];   // 32 KB: A dbuf 2x2048, B dbuf 2x6144 (u16)

    const int tid  = threadIdx.x;
    const int lane = tid & 63, wave = tid >> 6;
    const int quad = lane >> 4, l16 = lane & 15;
    const int wm = (wave & 1) * 32;          // row half (32 rows)
    const int wn = (wave >> 1) * 96;         // col half = one head
    const int m0 = blockIdx.x * 64, n0 = blockIdx.y * 192;
    const int K = DIMC;
    const int NT = K / 32;                   // 24

    const int lrow = lane >> 2, lchunk = lane & 3;
    const u16* gA = xb  + (size_t)(m0 + wave * 16 + lrow) * K + lchunk * 8;
    const u16* gB = Wab + (size_t)(n0 + wave * 48 + lrow) * K + lchunk * 8;

    // As[buf] = smem + buf*2048 (64x32); Bs[buf] = smem + 4096 + buf*6144 (192x32)
#define STAGE(buf, kt_) do {                                                  \
        const int _k0 = (kt_) * 32;                                           \
        u16* _as = smem + (buf) * 2048 + wave * 512;                          \
        u16* _bs = smem + 4096 + (buf) * 6144 + wave * 1536;                  \
        async_load16(gA + _k0,          _as);                                 \
        async_load16(gB + _k0,          _bs);                                 \
        async_load16(gB + _k0 + 16 * K, _bs + 512);                          \
        async_load16(gB + _k0 + 32 * K, _bs + 1024);                         \
    } while (0)

#define COMPUTE(buf) do {                                                     \
        const u16* _as = smem + (buf) * 2048;                                 \
        const u16* _bs = smem + 4096 + (buf) * 6144;                          \
        short8 af[2], bfr[6];                                                 \
        _Pragma("unroll")                                                     \
        for (int t = 0; t < 2; ++t)                                           \
            af[t] = *(const short8*)&_as[(wm + t * 16 + l16) * 32 + quad * 8];\
        _Pragma("unroll")                                                     \
        for (int t = 0; t < 6; ++t)                                           \
            bfr[t] = *(const short8*)&_bs[(wn + t * 16 + l16) * 32 + quad * 8];\
        _Pragma("unroll")                                                     \
        for (int mt = 0; mt < 2; ++mt)                                        \
            _Pragma("unroll")                                                 \
            for (int ct = 0; ct < 6; ++ct)                                    \
                acc[mt][ct] = __builtin_amdgcn_mfma_f32_16x16x32_bf16(        \
                    af[mt], bfr[ct], acc[mt][ct], 0, 0, 0);                   \
    } while (0)

    floatx4 acc[2][6] = {};
    STAGE(0, 0);
    STAGE(1, 1);
#pragma unroll 2
    for (int kt = 0; kt < NT - 2; ++kt) {
        const int buf = kt & 1;
        __asm__ volatile("s_waitcnt vmcnt(4)" ::: "memory");
        __asm__ volatile("s_barrier" ::: "memory");
        COMPUTE(buf);
        __asm__ volatile("s_barrier" ::: "memory");
        STAGE(buf, kt + 2);
    }
    __asm__ volatile("s_waitcnt vmcnt(4)" ::: "memory");
    __asm__ volatile("s_barrier" ::: "memory");
    COMPUTE(0);                                  // kt = 22
    __asm__ volatile("s_waitcnt vmcnt(0)" ::: "memory");
    __asm__ volatile("s_barrier" ::: "memory");  // cross-wave staging complete
    COMPUTE(1);                                  // kt = 23
    __syncthreads();                             // staging LDS dead -> P overlay
#undef STAGE
#undef COMPUTE

    // ---------------- fused attention epilogue (wave-local) ----------------
    const int b = blockIdx.x >> 5;               // m0 / 2048
    const int h = blockIdx.y * 2 + (wave >> 1);
    const u16* vbase = VsT + ((size_t)b * HEADS + h) * 4096;

    short8 bV[4][2];
#pragma unroll
    for (int nt2 = 0; nt2 < 4; ++nt2)
#pragma unroll
        for (int kk = 0; kk < 2; ++kk)
            bV[nt2][kk] = *(const short8*)
                &vbase[(nt2 * 16 + l16) * 64 + kk * 32 + quad * 8];

    u16* Pw = smem + wave * 2304;                // 32 x 72 bf16, per wave
    const int srcl0 = quad * 16 + (l16 >> 1);    // b-col p>>1, frag-local
    const int srcl1 = srcl0 + 8;

    short8 ones;
#pragma unroll
    for (int j = 0; j < 8; ++j) ones[j] = (short)0x3F80;   // bf16 1.0

#pragma unroll
    for (int mt = 0; mt < 2; ++mt) {
        // scores s_p = a_p * b_{p/2}; cols of wave tile: [0,64)=a, [64,96)=b
#pragma unroll
        for (int nt = 0; nt < 4; ++nt) {
            const int src = (nt & 1) ? srcl1 : srcl0;
#pragma unroll
            for (int r = 0; r < 4; ++r) {
                float bsh = __shfl(acc[mt][4 + (nt >> 1)][r], src, 64);
                float e = __expf(acc[mt][nt][r] * bsh);
                Pw[(mt * 16 + quad * 4 + r) * 72 + nt * 16 + l16] = f2bf(e);
            }
        }
        // PV for this 16-row tile (wave-local)
        short8 a0 = *(const short8*)&Pw[(mt * 16 + l16) * 72 + quad * 8];
        short8 a1 = *(const short8*)&Pw[(mt * 16 + l16) * 72 + 32 + quad * 8];
        floatx4 sacc = {};
        sacc = __builtin_amdgcn_mfma_f32_16x16x32_bf16(a0, ones, sacc, 0, 0, 0);
        sacc = __builtin_amdgcn_mfma_f32_16x16x32_bf16(a1, ones, sacc, 0, 0, 0);
        floatx4 accO[4] = {};
#pragma unroll
        for (int nt2 = 0; nt2 < 4; ++nt2) {
            accO[nt2] = __builtin_amdgcn_mfma_f32_16x16x32_bf16(a0, bV[nt2][0], accO[nt2], 0, 0, 0);
            accO[nt2] = __builtin_amdgcn_mfma_f32_16x16x32_bf16(a1, bV[nt2][1], accO[nt2], 0, 0, 0);
        }
        float inv[4];
#pragma unroll
        for (int r = 0; r < 4; ++r) inv[r] = 1.0f / (32.0f * sacc[r]);
#pragma unroll
        for (int nt2 = 0; nt2 < 4; ++nt2)
#pragma unroll
            for (int rr = 0; rr < 4; ++rr) {
                const size_t row = (size_t)(m0 + wm + mt * 16 + quad * 4 + rr);
                Hb[row * DIMC + h * 64 + nt2 * 16 + l16] =
                    f2bf(accO[nt2][rr] * inv[rr]);
            }
    }
}

// ---------------------------------------------------------------------------
extern "C" void kernel_launch(void* const* d_in, const int* in_sizes, int n_in,
                              void* d_out, int out_size, void* d_ws, size_t ws_size,
                              hipStream_t stream)
{
    const float* x  = (const float*)d_in[0];
    const float* Wa = (const float*)d_in[1];
    const float* Wb = (const float*)d_in[2];
    const float* Wv = (const float*)d_in[3];
    const float* Wp = (const float*)d_in[4];
    const float* bp = (const float*)d_in[5];
    float* out = (float*)d_out;

    char* ws = (char*)d_ws;
    u16*   xb    = (u16*)ws;   ws += (size_t)MROWS * DIMC * 2;   // 12.6 MB
    u16*   Wtcat = (u16*)ws;   ws += (size_t)NCAT * DIMC * 2;    // 2.9 MB
    u16*   Wpt   = (u16*)ws;   ws += (size_t)DIMC * DIMC * 2;    // 1.2 MB
    u16*   xs    = (u16*)ws;   ws += (size_t)256 * DIMC * 2;     // 0.4 MB
    u16*   VsT   = (u16*)ws;   ws += (size_t)48 * 4096 * 2;      // 0.4 MB
    u16*   Hb    = (u16*)ws;                                     // 12.6 MB

    dim3 blk(256);

    prep_kernel<<<dim3(3832), blk, 0, stream>>>(x, Wa, Wb, Wv, Wp,
                                                xb, Wtcat, Wpt, xs);

    vs_kernel<<<dim3(48), blk, 0, stream>>>(xs, Wtcat + (size_t)NAB * DIMC, VsT);

    gemm1_attn_kernel<<<dim3(MROWS / 64, NAB / 192), blk, 0, stream>>>(
        xb, Wtcat, VsT, Hb);

    gemm_bf16_kernel<false><<<dim3(MROWS / 64, DIMC / 128), blk, 0, stream>>>(
        Hb, Wpt, bp, out, DIMC, DIMC);
}

// Round 6
// 150.641 us; speedup vs baseline: 1.0361x; 1.0361x over previous
//
#include <hip/hip_runtime.h>
#include <hip/hip_bf16.h>
#include <cstddef>

#define DIMC   768
#define HEADS  12
#define BATCH  4
#define SEQ    2048
#define MROWS  (BATCH * SEQ)      // 8192
#define NCAT   1920               // Wtcat rows: 1152 (head-major [Wa|Wb]) + 768 (Wv)
#define NAB    1152

typedef unsigned short u16;
typedef __attribute__((ext_vector_type(8))) short short8;   // 8 bf16 = 4 VGPRs
typedef __attribute__((ext_vector_type(4))) float floatx4;  // MFMA C/D

__device__ inline u16 f2bf(float f) {
    union { float f; unsigned u; } v; v.f = f;
    unsigned u = v.u + 0x7FFF + ((v.u >> 16) & 1);   // RNE
    return (u16)(u >> 16);
}
__device__ inline float bf2f(u16 h) {
    union { unsigned u; float f; } v; v.u = ((unsigned)h) << 16;
    return v.f;
}

// async 16B/lane global->LDS; lane i lands at lptr + i*16 (wave-uniform base)
__device__ inline void async_load16(const void* g, void* l) {
    __builtin_amdgcn_global_load_lds(
        (const __attribute__((address_space(1))) void*)g,
        (__attribute__((address_space(3))) void*)l, 16, 0, 0);
}

// ---------------------------------------------------------------------------
// Fused prep, v2 — x read ONCE:
//  [0,768)       conv+pool: block (p, cchunk) owns rows [p*32,p*32+32) x
//                cols [c0,c0+256): writes xb bf16 patch AND the fp32 column
//                sum -> xs[p][c0+t] (identical numerics to the old 2 passes)
//  [768,1128)    Wtcat 64x64 tile-transpose from [Wa|Wb|Wv] (head-major ab)
//  [1128,1272)   Wpt from Wp
// ---------------------------------------------------------------------------
__global__ __launch_bounds__(256)
void prep_kernel(const float* __restrict__ x,
                 const float* __restrict__ Wa, const float* __restrict__ Wb,
                 const float* __restrict__ Wv, const float* __restrict__ Wp,
                 u16* __restrict__ xb, u16* __restrict__ Wtcat,
                 u16* __restrict__ Wpt, u16* __restrict__ xs)
{
    const int tid = threadIdx.x;
    const int bidg = blockIdx.x;
    if (bidg < 768) {
        const int p  = bidg / 3;                   // pooled row [0,256)
        const int c  = (bidg % 3) * 256 + tid;     // column
        const float* src = x + (size_t)p * 32 * DIMC + c;
        u16* dst = xb + (size_t)p * 32 * DIMC + c;
        float s = 0.f;
#pragma unroll
        for (int j = 0; j < 32; ++j) {
            const float v = src[(size_t)j * DIMC];
            s += v;
            dst[(size_t)j * DIMC] = f2bf(v);
        }
        xs[(size_t)p * DIMC + c] = f2bf(s);
        return;
    }
    __shared__ u16 tile[64 * 72];
    int bid = bidg - 768;
    const float* src; u16* dst; int n0, k0, ld, col0;
    bool remap = false;
    if (bid < 360) {
        int nt = bid / 12, kt = bid % 12;
        n0 = nt * 64; k0 = kt * 64; dst = Wtcat;
        if (n0 < 768)       { src = Wa; ld = 768; col0 = n0; remap = true; }
        else if (n0 < 1152) { src = Wb; ld = 384; col0 = n0 - 768; remap = true; }
        else                { src = Wv; ld = 768; col0 = n0 - 1152; }
    } else {
        int b2 = bid - 360;
        int nt = b2 / 12, kt = b2 % 12;
        n0 = nt * 64; k0 = kt * 64; dst = Wpt; src = Wp; ld = 768; col0 = n0;
    }
#pragma unroll
    for (int p = 0; p < 16; ++p) {
        int i = p * 256 + tid;
        int k = i >> 6, n = i & 63;
        tile[n * 72 + k] = f2bf(src[(size_t)(k0 + k) * ld + col0 + n]);
    }
    __syncthreads();
    int n = tid >> 2, kc = (tid & 3) * 16;
    int orow = n0 + n;
    int drow = orow;
    if (remap) {
        if (orow < 768) drow = (orow >> 6) * 96 + (orow & 63);              // Wa
        else { int c = orow - 768; drow = (c >> 5) * 96 + 64 + (c & 31); }  // Wb
    }
    uint4 o0 = *(uint4*)&tile[n * 72 + kc];
    uint4 o1 = *(uint4*)&tile[n * 72 + kc + 8];
    *(uint4*)&dst[(size_t)drow * DIMC + k0 + kc] = o0;
    *(uint4*)&dst[(size_t)drow * DIMC + k0 + kc + 8] = o1;
}

// ---------------------------------------------------------------------------
// bf16 MFMA GEMM — REVERTED to validated 128x128 (round-4 exact); gemm2 only.
// gemm2's 164-VGPR already allows 3 waves/SIMD; 64-wide retile regressed
// (halved MFMA/barrier, doubled B staging). Keep 128x128.
// ---------------------------------------------------------------------------
template<bool WRITE_BF16>
__global__ __launch_bounds__(256)
void gemm_bf16_kernel(const u16* __restrict__ A, const u16* __restrict__ Bt,
                      const float* __restrict__ bias, void* __restrict__ Cout,
                      int K, int ldC)
{
    __shared__ u16 As[2][4096];
    __shared__ u16 Bs[2][4096];

    const int tid  = threadIdx.x;
    const int lane = tid & 63, wave = tid >> 6;
    const int quad = lane >> 4, l16 = lane & 15;
    const int wm = (wave & 1) * 64, wn = (wave >> 1) * 64;
    const int m0 = blockIdx.x * 128, n0 = blockIdx.y * 128;

    const int lrow = lane >> 2, lchunk = lane & 3;
    const u16* gA = A  + (size_t)(m0 + wave * 32 + lrow) * K + lchunk * 8;
    const u16* gB = Bt + (size_t)(n0 + wave * 32 + lrow) * K + lchunk * 8;
    const int NT = K / 32;   // 24

#define STAGE(buf, kt_) do {                                                  \
        const int _k0 = (kt_) * 32;                                           \
        async_load16(gA + _k0,          &As[buf][wave * 1024]);               \
        async_load16(gA + _k0 + 16 * K, &As[buf][wave * 1024 + 512]);         \
        async_load16(gB + _k0,          &Bs[buf][wave * 1024]);               \
        async_load16(gB + _k0 + 16 * K, &Bs[buf][wave * 1024 + 512]);         \
    } while (0)

#define COMPUTE(buf) do {                                                     \
        short8 af[4], bf[4];                                                  \
        _Pragma("unroll")                                                     \
        for (int t = 0; t < 4; ++t) {                                         \
            af[t] = *(short8*)&As[buf][(wm + t * 16 + l16) * 32 + quad * 8];  \
            bf[t] = *(short8*)&Bs[buf][(wn + t * 16 + l16) * 32 + quad * 8];  \
        }                                                                     \
        _Pragma("unroll")                                                     \
        for (int mt = 0; mt < 4; ++mt)                                        \
            _Pragma("unroll")                                                 \
            for (int nt = 0; nt < 4; ++nt)                                    \
                acc[mt][nt] = __builtin_amdgcn_mfma_f32_16x16x32_bf16(        \
                    af[mt], bf[nt], acc[mt][nt], 0, 0, 0);                    \
    } while (0)

    floatx4 acc[4][4] = {};
    STAGE(0, 0);
    STAGE(1, 1);
#pragma unroll 2
    for (int kt = 0; kt < NT; ++kt) {
        const int buf = kt & 1;
        __asm__ volatile("s_waitcnt vmcnt(4)" ::: "memory");
        __asm__ volatile("s_barrier" ::: "memory");
        COMPUTE(buf);
        __asm__ volatile("s_barrier" ::: "memory");
        STAGE(buf, (kt + 2) % NT);
    }
#undef STAGE
#undef COMPUTE

#pragma unroll
    for (int mt = 0; mt < 4; ++mt)
#pragma unroll
        for (int nt = 0; nt < 4; ++nt) {
            const int gc = n0 + wn + nt * 16 + l16;
            const float bv = bias ? bias[gc] : 0.f;
#pragma unroll
            for (int r = 0; r < 4; ++r) {
                const int gr = m0 + wm + mt * 16 + quad * 4 + r;
                const float v = acc[mt][nt][r] + bv;
                if (WRITE_BF16) ((u16*)Cout)[(size_t)gr * ldC + gc] = f2bf(v);
                else            ((float*)Cout)[(size_t)gr * ldC + gc] = v;
            }
        }
}

// ---------------------------------------------------------------------------
// Vs kernel — unchanged (validated). VsT[bh][d][t] bf16.
// ---------------------------------------------------------------------------
__global__ __launch_bounds__(256)
void vs_kernel(const u16* __restrict__ xs, const u16* __restrict__ Wvt,
               u16* __restrict__ VsT)
{
    const int tid = threadIdx.x;
    const int lane = tid & 63, wave = tid >> 6;
    const int quad = lane >> 4, l16 = lane & 15;
    const int bh = blockIdx.x;
    const int b = bh / HEADS, h = bh % HEADS;
    const int K = DIMC;

    const u16* gA = Wvt + (size_t)(h * 64 + wave * 16 + l16) * K + quad * 8;
    const u16* gB = xs  + (size_t)(b * 64 + l16) * K + quad * 8;

    floatx4 acc[4] = {};
    for (int it = 0; it < 24; ++it) {
        short8 af = *(const short8*)(gA + it * 32);
        short8 bf[4];
#pragma unroll
        for (int nt = 0; nt < 4; ++nt)
            bf[nt] = *(const short8*)(gB + (size_t)nt * 16 * K + it * 32);
#pragma unroll
        for (int nt = 0; nt < 4; ++nt)
            acc[nt] = __builtin_amdgcn_mfma_f32_16x16x32_bf16(
                af, bf[nt], acc[nt], 0, 0, 0);
    }
#pragma unroll
    for (int nt = 0; nt < 4; ++nt)
#pragma unroll
        for (int r = 0; r < 4; ++r) {
            const int d = wave * 16 + quad * 4 + r;
            const int t = nt * 16 + l16;
            VsT[(size_t)bh * 4096 + d * 64 + t] = f2bf(acc[nt][r]);
        }
}

// ---------------------------------------------------------------------------
// FUSED gemm1 + attention, 64x192 (round-4 validated, unchanged). 4 waves;
// wave w owns rows (w&1)*32, head (w>>1). acc[2][6]; 3 blocks/CU; vmcnt(4).
// ---------------------------------------------------------------------------
__global__ __launch_bounds__(256, 3)
void gemm1_attn_kernel(const u16* __restrict__ xb, const u16* __restrict__ Wab,
                       const u16* __restrict__ VsT, u16* __restrict__ Hb)
{
    __shared__ u16 smem[16384];   // 32 KB: A dbuf 2x2048, B dbuf 2x6144 (u16)

    const int tid  = threadIdx.x;
    const int lane = tid & 63, wave = tid >> 6;
    const int quad = lane >> 4, l16 = lane & 15;
    const int wm = (wave & 1) * 32;          // row half (32 rows)
    const int wn = (wave >> 1) * 96;         // col half = one head
    const int m0 = blockIdx.x * 64, n0 = blockIdx.y * 192;
    const int K = DIMC;
    const int NT = K / 32;                   // 24

    const int lrow = lane >> 2, lchunk = lane & 3;
    const u16* gA = xb  + (size_t)(m0 + wave * 16 + lrow) * K + lchunk * 8;
    const u16* gB = Wab + (size_t)(n0 + wave * 48 + lrow) * K + lchunk * 8;

    // As[buf] = smem + buf*2048 (64x32); Bs[buf] = smem + 4096 + buf*6144 (192x32)
#define STAGE(buf, kt_) do {                                                  \
        const int _k0 = (kt_) * 32;                                           \
        u16* _as = smem + (buf) * 2048 + wave * 512;                          \
        u16* _bs = smem + 4096 + (buf) * 6144 + wave * 1536;                  \
        async_load16(gA + _k0,          _as);                                 \
        async_load16(gB + _k0,          _bs);                                 \
        async_load16(gB + _k0 + 16 * K, _bs + 512);                          \
        async_load16(gB + _k0 + 32 * K, _bs + 1024);                         \
    } while (0)

#define COMPUTE(buf) do {                                                     \
        const u16* _as = smem + (buf) * 2048;                                 \
        const u16* _bs = smem + 4096 + (buf) * 6144;                          \
        short8 af[2], bfr[6];                                                 \
        _Pragma("unroll")                                                     \
        for (int t = 0; t < 2; ++t)                                           \
            af[t] = *(const short8*)&_as[(wm + t * 16 + l16) * 32 + quad * 8];\
        _Pragma("unroll")                                                     \
        for (int t = 0; t < 6; ++t)                                           \
            bfr[t] = *(const short8*)&_bs[(wn + t * 16 + l16) * 32 + quad * 8];\
        _Pragma("unroll")                                                     \
        for (int mt = 0; mt < 2; ++mt)                                        \
            _Pragma("unroll")                                                 \
            for (int ct = 0; ct < 6; ++ct)                                    \
                acc[mt][ct] = __builtin_amdgcn_mfma_f32_16x16x32_bf16(        \
                    af[mt], bfr[ct], acc[mt][ct], 0, 0, 0);                   \
    } while (0)

    floatx4 acc[2][6] = {};
    STAGE(0, 0);
    STAGE(1, 1);
#pragma unroll 2
    for (int kt = 0; kt < NT - 2; ++kt) {
        const int buf = kt & 1;
        __asm__ volatile("s_waitcnt vmcnt(4)" ::: "memory");
        __asm__ volatile("s_barrier" ::: "memory");
        COMPUTE(buf);
        __asm__ volatile("s_barrier" ::: "memory");
        STAGE(buf, kt + 2);
    }
    __asm__ volatile("s_waitcnt vmcnt(4)" ::: "memory");
    __asm__ volatile("s_barrier" ::: "memory");
    COMPUTE(0);                                  // kt = 22
    __asm__ volatile("s_waitcnt vmcnt(0)" ::: "memory");
    __asm__ volatile("s_barrier" ::: "memory");  // cross-wave staging complete
    COMPUTE(1);                                  // kt = 23
    __syncthreads();                             // staging LDS dead -> P overlay
#undef STAGE
#undef COMPUTE

    // ---------------- fused attention epilogue (wave-local) ----------------
    const int b = blockIdx.x >> 5;               // m0 / 2048
    const int h = blockIdx.y * 2 + (wave >> 1);
    const u16* vbase = VsT + ((size_t)b * HEADS + h) * 4096;

    short8 bV[4][2];
#pragma unroll
    for (int nt2 = 0; nt2 < 4; ++nt2)
#pragma unroll
        for (int kk = 0; kk < 2; ++kk)
            bV[nt2][kk] = *(const short8*)
                &vbase[(nt2 * 16 + l16) * 64 + kk * 32 + quad * 8];

    u16* Pw = smem + wave * 2304;                // 32 x 72 bf16, per wave
    const int srcl0 = quad * 16 + (l16 >> 1);    // b-col p>>1, frag-local
    const int srcl1 = srcl0 + 8;

    short8 ones;
#pragma unroll
    for (int j = 0; j < 8; ++j) ones[j] = (short)0x3F80;   // bf16 1.0

#pragma unroll
    for (int mt = 0; mt < 2; ++mt) {
        // scores s_p = a_p * b_{p/2}; cols of wave tile: [0,64)=a, [64,96)=b
#pragma unroll
        for (int nt = 0; nt < 4; ++nt) {
            const int src = (nt & 1) ? srcl1 : srcl0;
#pragma unroll
            for (int r = 0; r < 4; ++r) {
                float bsh = __shfl(acc[mt][4 + (nt >> 1)][r], src, 64);
                float e = __expf(acc[mt][nt][r] * bsh);
                Pw[(mt * 16 + quad * 4 + r) * 72 + nt * 16 + l16] = f2bf(e);
            }
        }
        // PV for this 16-row tile (wave-local)
        short8 a0 = *(const short8*)&Pw[(mt * 16 + l16) * 72 + quad * 8];
        short8 a1 = *(const short8*)&Pw[(mt * 16 + l16) * 72 + 32 + quad * 8];
        floatx4 sacc = {};
        sacc = __builtin_amdgcn_mfma_f32_16x16x32_bf16(a0, ones, sacc, 0, 0, 0);
        sacc = __builtin_amdgcn_mfma_f32_16x16x32_bf16(a1, ones, sacc, 0, 0, 0);
        floatx4 accO[4] = {};
#pragma unroll
        for (int nt2 = 0; nt2 < 4; ++nt2) {
            accO[nt2] = __builtin_amdgcn_mfma_f32_16x16x32_bf16(a0, bV[nt2][0], accO[nt2], 0, 0, 0);
            accO[nt2] = __builtin_amdgcn_mfma_f32_16x16x32_bf16(a1, bV[nt2][1], accO[nt2], 0, 0, 0);
        }
        float inv[4];
#pragma unroll
        for (int r = 0; r < 4; ++r) inv[r] = 1.0f / (32.0f * sacc[r]);
#pragma unroll
        for (int nt2 = 0; nt2 < 4; ++nt2)
#pragma unroll
            for (int rr = 0; rr < 4; ++rr) {
                const size_t row = (size_t)(m0 + wm + mt * 16 + quad * 4 + rr);
                Hb[row * DIMC + h * 64 + nt2 * 16 + l16] =
                    f2bf(accO[nt2][rr] * inv[rr]);
            }
    }
}

// ---------------------------------------------------------------------------
extern "C" void kernel_launch(void* const* d_in, const int* in_sizes, int n_in,
                              void* d_out, int out_size, void* d_ws, size_t ws_size,
                              hipStream_t stream)
{
    const float* x  = (const float*)d_in[0];
    const float* Wa = (const float*)d_in[1];
    const float* Wb = (const float*)d_in[2];
    const float* Wv = (const float*)d_in[3];
    const float* Wp = (const float*)d_in[4];
    const float* bp = (const float*)d_in[5];
    float* out = (float*)d_out;

    char* ws = (char*)d_ws;
    u16*   xb    = (u16*)ws;   ws += (size_t)MROWS * DIMC * 2;   // 12.6 MB
    u16*   Wtcat = (u16*)ws;   ws += (size_t)NCAT * DIMC * 2;    // 2.9 MB
    u16*   Wpt   = (u16*)ws;   ws += (size_t)DIMC * DIMC * 2;    // 1.2 MB
    u16*   xs    = (u16*)ws;   ws += (size_t)256 * DIMC * 2;     // 0.4 MB
    u16*   VsT   = (u16*)ws;   ws += (size_t)48 * 4096 * 2;      // 0.4 MB
    u16*   Hb    = (u16*)ws;                                     // 12.6 MB

    dim3 blk(256);

    prep_kernel<<<dim3(1272), blk, 0, stream>>>(x, Wa, Wb, Wv, Wp,
                                                xb, Wtcat, Wpt, xs);

    vs_kernel<<<dim3(48), blk, 0, stream>>>(xs, Wtcat + (size_t)NAB * DIMC, VsT);

    gemm1_attn_kernel<<<dim3(MROWS / 64, NAB / 192), blk, 0, stream>>>(
        xb, Wtcat, VsT, Hb);

    gemm_bf16_kernel<false><<<dim3(MROWS / 128, DIMC / 128), blk, 0, stream>>>(
        Hb, Wpt, bp, out, DIMC, DIMC);
}

// Round 7
// 147.704 us; speedup vs baseline: 1.0567x; 1.0199x over previous
//
#include <hip/hip_runtime.h>
#include <hip/hip_bf16.h>
#include <cstddef>

#define DIMC   768
#define HEADS  12
#define BATCH  4
#define SEQ    2048
#define MROWS  (BATCH * SEQ)      // 8192
#define NCAT   1920               // Wtcat rows: 1152 (head-major [Wa|Wb]) + 768 (Wv)
#define NAB    1152

typedef unsigned short u16;
typedef __attribute__((ext_vector_type(8))) short short8;   // 8 bf16 = 4 VGPRs
typedef __attribute__((ext_vector_type(4))) float floatx4;  // MFMA C/D

__device__ inline u16 f2bf(float f) {
    union { float f; unsigned u; } v; v.f = f;
    unsigned u = v.u + 0x7FFF + ((v.u >> 16) & 1);   // RNE
    return (u16)(u >> 16);
}
__device__ inline float bf2f(u16 h) {
    union { unsigned u; float f; } v; v.u = ((unsigned)h) << 16;
    return v.f;
}

// async 16B/lane global->LDS; lane i lands at lptr + i*16 (wave-uniform base)
__device__ inline void async_load16(const void* g, void* l) {
    __builtin_amdgcn_global_load_lds(
        (const __attribute__((address_space(1))) void*)g,
        (__attribute__((address_space(3))) void*)l, 16, 0, 0);
}

// ---------------------------------------------------------------------------
// Fused prep, v2 (round-6 validated, unchanged):
//  [0,768)       conv+pool: x read once -> xb bf16 + xs column sums
//  [768,1128)    Wtcat 64x64 tile-transpose from [Wa|Wb|Wv] (head-major ab)
//  [1128,1272)   Wpt from Wp
// ---------------------------------------------------------------------------
__global__ __launch_bounds__(256)
void prep_kernel(const float* __restrict__ x,
                 const float* __restrict__ Wa, const float* __restrict__ Wb,
                 const float* __restrict__ Wv, const float* __restrict__ Wp,
                 u16* __restrict__ xb, u16* __restrict__ Wtcat,
                 u16* __restrict__ Wpt, u16* __restrict__ xs)
{
    const int tid = threadIdx.x;
    const int bidg = blockIdx.x;
    if (bidg < 768) {
        const int p  = bidg / 3;                   // pooled row [0,256)
        const int c  = (bidg % 3) * 256 + tid;     // column
        const float* src = x + (size_t)p * 32 * DIMC + c;
        u16* dst = xb + (size_t)p * 32 * DIMC + c;
        float s = 0.f;
#pragma unroll
        for (int j = 0; j < 32; ++j) {
            const float v = src[(size_t)j * DIMC];
            s += v;
            dst[(size_t)j * DIMC] = f2bf(v);
        }
        xs[(size_t)p * DIMC + c] = f2bf(s);
        return;
    }
    __shared__ u16 tile[64 * 72];
    int bid = bidg - 768;
    const float* src; u16* dst; int n0, k0, ld, col0;
    bool remap = false;
    if (bid < 360) {
        int nt = bid / 12, kt = bid % 12;
        n0 = nt * 64; k0 = kt * 64; dst = Wtcat;
        if (n0 < 768)       { src = Wa; ld = 768; col0 = n0; remap = true; }
        else if (n0 < 1152) { src = Wb; ld = 384; col0 = n0 - 768; remap = true; }
        else                { src = Wv; ld = 768; col0 = n0 - 1152; }
    } else {
        int b2 = bid - 360;
        int nt = b2 / 12, kt = b2 % 12;
        n0 = nt * 64; k0 = kt * 64; dst = Wpt; src = Wp; ld = 768; col0 = n0;
    }
#pragma unroll
    for (int p = 0; p < 16; ++p) {
        int i = p * 256 + tid;
        int k = i >> 6, n = i & 63;
        tile[n * 72 + k] = f2bf(src[(size_t)(k0 + k) * ld + col0 + n]);
    }
    __syncthreads();
    int n = tid >> 2, kc = (tid & 3) * 16;
    int orow = n0 + n;
    int drow = orow;
    if (remap) {
        if (orow < 768) drow = (orow >> 6) * 96 + (orow & 63);              // Wa
        else { int c = orow - 768; drow = (c >> 5) * 96 + 64 + (c & 31); }  // Wb
    }
    uint4 o0 = *(uint4*)&tile[n * 72 + kc];
    uint4 o1 = *(uint4*)&tile[n * 72 + kc + 8];
    *(uint4*)&dst[(size_t)drow * DIMC + k0 + kc] = o0;
    *(uint4*)&dst[(size_t)drow * DIMC + k0 + kc + 8] = o1;
}

// ---------------------------------------------------------------------------
// bf16 MFMA GEMM 128x128 (validated) — now 1-D grid with XCD-chunk swizzle.
// Logical id w = (p&7)*(nwg/8) + p>>3 (bijective, nwg%8==0); A-panel-major
// order (row = w/nby, col = w%nby) so blocks sharing an A panel are
// consecutive within one XCD chunk -> A+B L2-resident per XCD.
// Work per block bit-identical to round 6.
// ---------------------------------------------------------------------------
template<bool WRITE_BF16>
__global__ __launch_bounds__(256)
void gemm_bf16_kernel(const u16* __restrict__ A, const u16* __restrict__ Bt,
                      const float* __restrict__ bias, void* __restrict__ Cout,
                      int K, int ldC, int nby)
{
    __shared__ u16 As[2][4096];
    __shared__ u16 Bs[2][4096];

    const int tid  = threadIdx.x;
    const int lane = tid & 63, wave = tid >> 6;
    const int quad = lane >> 4, l16 = lane & 15;
    const int wm = (wave & 1) * 64, wn = (wave >> 1) * 64;

    const int p = blockIdx.x;
    const int w = (p & 7) * ((int)gridDim.x >> 3) + (p >> 3);
    const int m0 = (w / nby) * 128, n0 = (w % nby) * 128;

    const int lrow = lane >> 2, lchunk = lane & 3;
    const u16* gA = A  + (size_t)(m0 + wave * 32 + lrow) * K + lchunk * 8;
    const u16* gB = Bt + (size_t)(n0 + wave * 32 + lrow) * K + lchunk * 8;
    const int NT = K / 32;   // 24

#define STAGE(buf, kt_) do {                                                  \
        const int _k0 = (kt_) * 32;                                           \
        async_load16(gA + _k0,          &As[buf][wave * 1024]);               \
        async_load16(gA + _k0 + 16 * K, &As[buf][wave * 1024 + 512]);         \
        async_load16(gB + _k0,          &Bs[buf][wave * 1024]);               \
        async_load16(gB + _k0 + 16 * K, &Bs[buf][wave * 1024 + 512]);         \
    } while (0)

#define COMPUTE(buf) do {                                                     \
        short8 af[4], bf[4];                                                  \
        _Pragma("unroll")                                                     \
        for (int t = 0; t < 4; ++t) {                                         \
            af[t] = *(short8*)&As[buf][(wm + t * 16 + l16) * 32 + quad * 8];  \
            bf[t] = *(short8*)&Bs[buf][(wn + t * 16 + l16) * 32 + quad * 8];  \
        }                                                                     \
        _Pragma("unroll")                                                     \
        for (int mt = 0; mt < 4; ++mt)                                        \
            _Pragma("unroll")                                                 \
            for (int nt = 0; nt < 4; ++nt)                                    \
                acc[mt][nt] = __builtin_amdgcn_mfma_f32_16x16x32_bf16(        \
                    af[mt], bf[nt], acc[mt][nt], 0, 0, 0);                    \
    } while (0)

    floatx4 acc[4][4] = {};
    STAGE(0, 0);
    STAGE(1, 1);
#pragma unroll 2
    for (int kt = 0; kt < NT; ++kt) {
        const int buf = kt & 1;
        __asm__ volatile("s_waitcnt vmcnt(4)" ::: "memory");
        __asm__ volatile("s_barrier" ::: "memory");
        COMPUTE(buf);
        __asm__ volatile("s_barrier" ::: "memory");
        STAGE(buf, (kt + 2) % NT);
    }
#undef STAGE
#undef COMPUTE

#pragma unroll
    for (int mt = 0; mt < 4; ++mt)
#pragma unroll
        for (int nt = 0; nt < 4; ++nt) {
            const int gc = n0 + wn + nt * 16 + l16;
            const float bv = bias ? bias[gc] : 0.f;
#pragma unroll
            for (int r = 0; r < 4; ++r) {
                const int gr = m0 + wm + mt * 16 + quad * 4 + r;
                const float v = acc[mt][nt][r] + bv;
                if (WRITE_BF16) ((u16*)Cout)[(size_t)gr * ldC + gc] = f2bf(v);
                else            ((float*)Cout)[(size_t)gr * ldC + gc] = v;
            }
        }
}

// ---------------------------------------------------------------------------
// Vs kernel — unchanged (validated). VsT[bh][d][t] bf16.
// ---------------------------------------------------------------------------
__global__ __launch_bounds__(256)
void vs_kernel(const u16* __restrict__ xs, const u16* __restrict__ Wvt,
               u16* __restrict__ VsT)
{
    const int tid = threadIdx.x;
    const int lane = tid & 63, wave = tid >> 6;
    const int quad = lane >> 4, l16 = lane & 15;
    const int bh = blockIdx.x;
    const int b = bh / HEADS, h = bh % HEADS;
    const int K = DIMC;

    const u16* gA = Wvt + (size_t)(h * 64 + wave * 16 + l16) * K + quad * 8;
    const u16* gB = xs  + (size_t)(b * 64 + l16) * K + quad * 8;

    floatx4 acc[4] = {};
    for (int it = 0; it < 24; ++it) {
        short8 af = *(const short8*)(gA + it * 32);
        short8 bf[4];
#pragma unroll
        for (int nt = 0; nt < 4; ++nt)
            bf[nt] = *(const short8*)(gB + (size_t)nt * 16 * K + it * 32);
#pragma unroll
        for (int nt = 0; nt < 4; ++nt)
            acc[nt] = __builtin_amdgcn_mfma_f32_16x16x32_bf16(
                af, bf[nt], acc[nt], 0, 0, 0);
    }
#pragma unroll
    for (int nt = 0; nt < 4; ++nt)
#pragma unroll
        for (int r = 0; r < 4; ++r) {
            const int d = wave * 16 + quad * 4 + r;
            const int t = nt * 16 + l16;
            VsT[(size_t)bh * 4096 + d * 64 + t] = f2bf(acc[nt][r]);
        }
}

// ---------------------------------------------------------------------------
// FUSED gemm1 + attention, 64x192 (round-4 validated) — now 1-D grid with
// XCD-chunk swizzle, A-panel-major logical order (same scheme as gemm2).
// Per-XCD working set: A 16x96KB=1.5MB + Wab 1.7MB -> L2-resident.
// ---------------------------------------------------------------------------
__global__ __launch_bounds__(256, 3)
void gemm1_attn_kernel(const u16* __restrict__ xb, const u16* __restrict__ Wab,
                       const u16* __restrict__ VsT, u16* __restrict__ Hb)
{
    __shared__ u16 smem[16384];   // 32 KB: A dbuf 2x2048, B dbuf 2x6144 (u16)

    const int tid  = threadIdx.x;
    const int lane = tid & 63, wave = tid >> 6;
    const int quad = lane >> 4, l16 = lane & 15;
    const int wm = (wave & 1) * 32;          // row half (32 rows)
    const int wn = (wave >> 1) * 96;         // col half = one head

    const int p = blockIdx.x;                // [0,768)
    const int w = (p & 7) * 96 + (p >> 3);   // bijective XCD-chunk swizzle
    const int rowb = w / 6, colb = w % 6;    // A-panel-major
    const int m0 = rowb * 64, n0 = colb * 192;

    const int K = DIMC;
    const int NT = K / 32;                   // 24

    const int lrow = lane >> 2, lchunk = lane & 3;
    const u16* gA = xb  + (size_t)(m0 + wave * 16 + lrow) * K + lchunk * 8;
    const u16* gB = Wab + (size_t)(n0 + wave * 48 + lrow) * K + lchunk * 8;

    // As[buf] = smem + buf*2048 (64x32); Bs[buf] = smem + 4096 + buf*6144 (192x32)
#define STAGE(buf, kt_) do {                                                  \
        const int _k0 = (kt_) * 32;                                           \
        u16* _as = smem + (buf) * 2048 + wave * 512;                          \
        u16* _bs = smem + 4096 + (buf) * 6144 + wave * 1536;                  \
        async_load16(gA + _k0,          _as);                                 \
        async_load16(gB + _k0,          _bs);                                 \
        async_load16(gB + _k0 + 16 * K, _bs + 512);                          \
        async_load16(gB + _k0 + 32 * K, _bs + 1024);                         \
    } while (0)

#define COMPUTE(buf) do {                                                     \
        const u16* _as = smem + (buf) * 2048;                                 \
        const u16* _bs = smem + 4096 + (buf) * 6144;                          \
        short8 af[2], bfr[6];                                                 \
        _Pragma("unroll")                                                     \
        for (int t = 0; t < 2; ++t)                                           \
            af[t] = *(const short8*)&_as[(wm + t * 16 + l16) * 32 + quad * 8];\
        _Pragma("unroll")                                                     \
        for (int t = 0; t < 6; ++t)                                           \
            bfr[t] = *(const short8*)&_bs[(wn + t * 16 + l16) * 32 + quad * 8];\
        _Pragma("unroll")                                                     \
        for (int mt = 0; mt < 2; ++mt)                                        \
            _Pragma("unroll")                                                 \
            for (int ct = 0; ct < 6; ++ct)                                    \
                acc[mt][ct] = __builtin_amdgcn_mfma_f32_16x16x32_bf16(        \
                    af[mt], bfr[ct], acc[mt][ct], 0, 0, 0);                   \
    } while (0)

    floatx4 acc[2][6] = {};
    STAGE(0, 0);
    STAGE(1, 1);
#pragma unroll 2
    for (int kt = 0; kt < NT - 2; ++kt) {
        const int buf = kt & 1;
        __asm__ volatile("s_waitcnt vmcnt(4)" ::: "memory");
        __asm__ volatile("s_barrier" ::: "memory");
        COMPUTE(buf);
        __asm__ volatile("s_barrier" ::: "memory");
        STAGE(buf, kt + 2);
    }
    __asm__ volatile("s_waitcnt vmcnt(4)" ::: "memory");
    __asm__ volatile("s_barrier" ::: "memory");
    COMPUTE(0);                                  // kt = 22
    __asm__ volatile("s_waitcnt vmcnt(0)" ::: "memory");
    __asm__ volatile("s_barrier" ::: "memory");  // cross-wave staging complete
    COMPUTE(1);                                  // kt = 23
    __syncthreads();                             // staging LDS dead -> P overlay
#undef STAGE
#undef COMPUTE

    // ---------------- fused attention epilogue (wave-local) ----------------
    const int b = rowb >> 5;                     // m0 / 2048
    const int h = colb * 2 + (wave >> 1);
    const u16* vbase = VsT + ((size_t)b * HEADS + h) * 4096;

    short8 bV[4][2];
#pragma unroll
    for (int nt2 = 0; nt2 < 4; ++nt2)
#pragma unroll
        for (int kk = 0; kk < 2; ++kk)
            bV[nt2][kk] = *(const short8*)
                &vbase[(nt2 * 16 + l16) * 64 + kk * 32 + quad * 8];

    u16* Pw = smem + wave * 2304;                // 32 x 72 bf16, per wave
    const int srcl0 = quad * 16 + (l16 >> 1);    // b-col p>>1, frag-local
    const int srcl1 = srcl0 + 8;

    short8 ones;
#pragma unroll
    for (int j = 0; j < 8; ++j) ones[j] = (short)0x3F80;   // bf16 1.0

#pragma unroll
    for (int mt = 0; mt < 2; ++mt) {
        // scores s_p = a_p * b_{p/2}; cols of wave tile: [0,64)=a, [64,96)=b
#pragma unroll
        for (int nt = 0; nt < 4; ++nt) {
            const int src = (nt & 1) ? srcl1 : srcl0;
#pragma unroll
            for (int r = 0; r < 4; ++r) {
                float bsh = __shfl(acc[mt][4 + (nt >> 1)][r], src, 64);
                float e = __expf(acc[mt][nt][r] * bsh);
                Pw[(mt * 16 + quad * 4 + r) * 72 + nt * 16 + l16] = f2bf(e);
            }
        }
        // PV for this 16-row tile (wave-local)
        short8 a0 = *(const short8*)&Pw[(mt * 16 + l16) * 72 + quad * 8];
        short8 a1 = *(const short8*)&Pw[(mt * 16 + l16) * 72 + 32 + quad * 8];
        floatx4 sacc = {};
        sacc = __builtin_amdgcn_mfma_f32_16x16x32_bf16(a0, ones, sacc, 0, 0, 0);
        sacc = __builtin_amdgcn_mfma_f32_16x16x32_bf16(a1, ones, sacc, 0, 0, 0);
        floatx4 accO[4] = {};
#pragma unroll
        for (int nt2 = 0; nt2 < 4; ++nt2) {
            accO[nt2] = __builtin_amdgcn_mfma_f32_16x16x32_bf16(a0, bV[nt2][0], accO[nt2], 0, 0, 0);
            accO[nt2] = __builtin_amdgcn_mfma_f32_16x16x32_bf16(a1, bV[nt2][1], accO[nt2], 0, 0, 0);
        }
        float inv[4];
#pragma unroll
        for (int r = 0; r < 4; ++r) inv[r] = 1.0f / (32.0f * sacc[r]);
#pragma unroll
        for (int nt2 = 0; nt2 < 4; ++nt2)
#pragma unroll
            for (int rr = 0; rr < 4; ++rr) {
                const size_t row = (size_t)(m0 + wm + mt * 16 + quad * 4 + rr);
                Hb[row * DIMC + h * 64 + nt2 * 16 + l16] =
                    f2bf(accO[nt2][rr] * inv[rr]);
            }
    }
}

// ---------------------------------------------------------------------------
extern "C" void kernel_launch(void* const* d_in, const int* in_sizes, int n_in,
                              void* d_out, int out_size, void* d_ws, size_t ws_size,
                              hipStream_t stream)
{
    const float* x  = (const float*)d_in[0];
    const float* Wa = (const float*)d_in[1];
    const float* Wb = (const float*)d_in[2];
    const float* Wv = (const float*)d_in[3];
    const float* Wp = (const float*)d_in[4];
    const float* bp = (const float*)d_in[5];
    float* out = (float*)d_out;

    char* ws = (char*)d_ws;
    u16*   xb    = (u16*)ws;   ws += (size_t)MROWS * DIMC * 2;   // 12.6 MB
    u16*   Wtcat = (u16*)ws;   ws += (size_t)NCAT * DIMC * 2;    // 2.9 MB
    u16*   Wpt   = (u16*)ws;   ws += (size_t)DIMC * DIMC * 2;    // 1.2 MB
    u16*   xs    = (u16*)ws;   ws += (size_t)256 * DIMC * 2;     // 0.4 MB
    u16*   VsT   = (u16*)ws;   ws += (size_t)48 * 4096 * 2;      // 0.4 MB
    u16*   Hb    = (u16*)ws;                                     // 12.6 MB

    dim3 blk(256);

    prep_kernel<<<dim3(1272), blk, 0, stream>>>(x, Wa, Wb, Wv, Wp,
                                                xb, Wtcat, Wpt, xs);

    vs_kernel<<<dim3(48), blk, 0, stream>>>(xs, Wtcat + (size_t)NAB * DIMC, VsT);

    gemm1_attn_kernel<<<dim3(768), blk, 0, stream>>>(xb, Wtcat, VsT, Hb);

    gemm_bf16_kernel<false><<<dim3(384), blk, 0, stream>>>(
        Hb, Wpt, bp, out, DIMC, DIMC, 6);
}

// Round 8
// 146.562 us; speedup vs baseline: 1.0649x; 1.0078x over previous
//
#include <hip/hip_runtime.h>
#include <hip/hip_bf16.h>
#include <cstddef>

#define DIMC   768
#define HEADS  12
#define BATCH  4
#define SEQ    2048
#define MROWS  (BATCH * SEQ)      // 8192
#define NCAT   1920               // Wtcat rows: 1152 (head-major [Wa|Wb]) + 768 (Wv)
#define NAB    1152

typedef unsigned short u16;
typedef __attribute__((ext_vector_type(8))) short short8;   // 8 bf16 = 4 VGPRs
typedef __attribute__((ext_vector_type(4))) float floatx4;  // MFMA C/D

__device__ inline u16 f2bf(float f) {
    union { float f; unsigned u; } v; v.f = f;
    unsigned u = v.u + 0x7FFF + ((v.u >> 16) & 1);   // RNE
    return (u16)(u >> 16);
}
__device__ inline float bf2f(u16 h) {
    union { unsigned u; float f; } v; v.u = ((unsigned)h) << 16;
    return v.f;
}

// async 16B/lane global->LDS; lane i lands at lptr + i*16 (wave-uniform base)
__device__ inline void async_load16(const void* g, void* l) {
    __builtin_amdgcn_global_load_lds(
        (const __attribute__((address_space(1))) void*)g,
        (__attribute__((address_space(3))) void*)l, 16, 0, 0);
}

// ---------------------------------------------------------------------------
// Fused prep, v3:
//  [0,256)       conv+pool VECTORIZED: one block per pooled row p; lanes
//                0..191 own 4 cols each: float4 load, uint2 bf16 store,
//                fp32 column sums -> xs (same per-column sum order as v2:
//                j ascending -> bit-identical)
//  [256,616)     Wtcat 64x64 tile-transpose from [Wa|Wb|Wv] (head-major ab)
//  [616,760)     Wpt from Wp
// ---------------------------------------------------------------------------
__global__ __launch_bounds__(256)
void prep_kernel(const float* __restrict__ x,
                 const float* __restrict__ Wa, const float* __restrict__ Wb,
                 const float* __restrict__ Wv, const float* __restrict__ Wp,
                 u16* __restrict__ xb, u16* __restrict__ Wtcat,
                 u16* __restrict__ Wpt, u16* __restrict__ xs)
{
    const int tid = threadIdx.x;
    const int bidg = blockIdx.x;
    if (bidg < 256) {
        const int p = bidg;                        // pooled row [0,256)
        if (tid < 192) {
            const float4* src = (const float4*)(x + (size_t)p * 32 * DIMC) + tid;
            u16* dstb = xb + (size_t)p * 32 * DIMC + tid * 4;
            float s0 = 0.f, s1 = 0.f, s2 = 0.f, s3 = 0.f;
#pragma unroll
            for (int j = 0; j < 32; ++j) {
                const float4 v = src[(size_t)j * (DIMC / 4)];
                s0 += v.x; s1 += v.y; s2 += v.z; s3 += v.w;
                u16 t4[4] = { f2bf(v.x), f2bf(v.y), f2bf(v.z), f2bf(v.w) };
                *(uint2*)&dstb[(size_t)j * DIMC] = *(uint2*)t4;
            }
            u16 o4[4] = { f2bf(s0), f2bf(s1), f2bf(s2), f2bf(s3) };
            *(uint2*)&xs[(size_t)p * DIMC + tid * 4] = *(uint2*)o4;
        }
        return;
    }
    __shared__ u16 tile[64 * 72];
    int bid = bidg - 256;
    const float* src; u16* dst; int n0, k0, ld, col0;
    bool remap = false;
    if (bid < 360) {
        int nt = bid / 12, kt = bid % 12;
        n0 = nt * 64; k0 = kt * 64; dst = Wtcat;
        if (n0 < 768)       { src = Wa; ld = 768; col0 = n0; remap = true; }
        else if (n0 < 1152) { src = Wb; ld = 384; col0 = n0 - 768; remap = true; }
        else                { src = Wv; ld = 768; col0 = n0 - 1152; }
    } else {
        int b2 = bid - 360;
        int nt = b2 / 12, kt = b2 % 12;
        n0 = nt * 64; k0 = kt * 64; dst = Wpt; src = Wp; ld = 768; col0 = n0;
    }
#pragma unroll
    for (int p = 0; p < 16; ++p) {
        int i = p * 256 + tid;
        int k = i >> 6, n = i & 63;
        tile[n * 72 + k] = f2bf(src[(size_t)(k0 + k) * ld + col0 + n]);
    }
    __syncthreads();
    int n = tid >> 2, kc = (tid & 3) * 16;
    int orow = n0 + n;
    int drow = orow;
    if (remap) {
        if (orow < 768) drow = (orow >> 6) * 96 + (orow & 63);              // Wa
        else { int c = orow - 768; drow = (c >> 5) * 96 + 64 + (c & 31); }  // Wb
    }
    uint4 o0 = *(uint4*)&tile[n * 72 + kc];
    uint4 o1 = *(uint4*)&tile[n * 72 + kc + 8];
    *(uint4*)&dst[(size_t)drow * DIMC + k0 + kc] = o0;
    *(uint4*)&dst[(size_t)drow * DIMC + k0 + kc + 8] = o1;
}

// ---------------------------------------------------------------------------
// bf16 MFMA GEMM 128x128 (validated) — 1-D grid, XCD-chunk swizzle (round 7).
// ---------------------------------------------------------------------------
template<bool WRITE_BF16>
__global__ __launch_bounds__(256)
void gemm_bf16_kernel(const u16* __restrict__ A, const u16* __restrict__ Bt,
                      const float* __restrict__ bias, void* __restrict__ Cout,
                      int K, int ldC, int nby)
{
    __shared__ u16 As[2][4096];
    __shared__ u16 Bs[2][4096];

    const int tid  = threadIdx.x;
    const int lane = tid & 63, wave = tid >> 6;
    const int quad = lane >> 4, l16 = lane & 15;
    const int wm = (wave & 1) * 64, wn = (wave >> 1) * 64;

    const int p = blockIdx.x;
    const int w = (p & 7) * ((int)gridDim.x >> 3) + (p >> 3);
    const int m0 = (w / nby) * 128, n0 = (w % nby) * 128;

    const int lrow = lane >> 2, lchunk = lane & 3;
    const u16* gA = A  + (size_t)(m0 + wave * 32 + lrow) * K + lchunk * 8;
    const u16* gB = Bt + (size_t)(n0 + wave * 32 + lrow) * K + lchunk * 8;
    const int NT = K / 32;   // 24

#define STAGE(buf, kt_) do {                                                  \
        const int _k0 = (kt_) * 32;                                           \
        async_load16(gA + _k0,          &As[buf][wave * 1024]);               \
        async_load16(gA + _k0 + 16 * K, &As[buf][wave * 1024 + 512]);         \
        async_load16(gB + _k0,          &Bs[buf][wave * 1024]);               \
        async_load16(gB + _k0 + 16 * K, &Bs[buf][wave * 1024 + 512]);         \
    } while (0)

#define COMPUTE(buf) do {                                                     \
        short8 af[4], bf[4];                                                  \
        _Pragma("unroll")                                                     \
        for (int t = 0; t < 4; ++t) {                                         \
            af[t] = *(short8*)&As[buf][(wm + t * 16 + l16) * 32 + quad * 8];  \
            bf[t] = *(short8*)&Bs[buf][(wn + t * 16 + l16) * 32 + quad * 8];  \
        }                                                                     \
        _Pragma("unroll")                                                     \
        for (int mt = 0; mt < 4; ++mt)                                        \
            _Pragma("unroll")                                                 \
            for (int nt = 0; nt < 4; ++nt)                                    \
                acc[mt][nt] = __builtin_amdgcn_mfma_f32_16x16x32_bf16(        \
                    af[mt], bf[nt], acc[mt][nt], 0, 0, 0);                    \
    } while (0)

    floatx4 acc[4][4] = {};
    STAGE(0, 0);
    STAGE(1, 1);
#pragma unroll 2
    for (int kt = 0; kt < NT; ++kt) {
        const int buf = kt & 1;
        __asm__ volatile("s_waitcnt vmcnt(4)" ::: "memory");
        __asm__ volatile("s_barrier" ::: "memory");
        COMPUTE(buf);
        __asm__ volatile("s_barrier" ::: "memory");
        STAGE(buf, (kt + 2) % NT);
    }
#undef STAGE
#undef COMPUTE

#pragma unroll
    for (int mt = 0; mt < 4; ++mt)
#pragma unroll
        for (int nt = 0; nt < 4; ++nt) {
            const int gc = n0 + wn + nt * 16 + l16;
            const float bv = bias ? bias[gc] : 0.f;
#pragma unroll
            for (int r = 0; r < 4; ++r) {
                const int gr = m0 + wm + mt * 16 + quad * 4 + r;
                const float v = acc[mt][nt][r] + bv;
                if (WRITE_BF16) ((u16*)Cout)[(size_t)gr * ldC + gc] = f2bf(v);
                else            ((float*)Cout)[(size_t)gr * ldC + gc] = v;
            }
        }
}

// ---------------------------------------------------------------------------
// Vs kernel — 2-way t-split for latency (96 blocks; was 48). Per-output
// accumulation chain unchanged -> bit-identical VsT.
// ---------------------------------------------------------------------------
__global__ __launch_bounds__(256)
void vs_kernel(const u16* __restrict__ xs, const u16* __restrict__ Wvt,
               u16* __restrict__ VsT)
{
    const int tid = threadIdx.x;
    const int lane = tid & 63, wave = tid >> 6;
    const int quad = lane >> 4, l16 = lane & 15;
    const int bh = blockIdx.x >> 1, th = blockIdx.x & 1;
    const int b = bh / HEADS, h = bh % HEADS;
    const int K = DIMC;

    const u16* gA = Wvt + (size_t)(h * 64 + wave * 16 + l16) * K + quad * 8;
    const u16* gB = xs  + (size_t)(b * 64 + th * 32 + l16) * K + quad * 8;

    floatx4 acc[2] = {};
    for (int it = 0; it < 24; ++it) {
        short8 af = *(const short8*)(gA + it * 32);
        short8 bf[2];
#pragma unroll
        for (int nt = 0; nt < 2; ++nt)
            bf[nt] = *(const short8*)(gB + (size_t)nt * 16 * K + it * 32);
#pragma unroll
        for (int nt = 0; nt < 2; ++nt)
            acc[nt] = __builtin_amdgcn_mfma_f32_16x16x32_bf16(
                af, bf[nt], acc[nt], 0, 0, 0);
    }
#pragma unroll
    for (int nt = 0; nt < 2; ++nt)
#pragma unroll
        for (int r = 0; r < 4; ++r) {
            const int d = wave * 16 + quad * 4 + r;
            const int t = th * 32 + nt * 16 + l16;
            VsT[(size_t)bh * 4096 + d * 64 + t] = f2bf(acc[nt][r]);
        }
}

// ---------------------------------------------------------------------------
// FUSED gemm1 + attention, 64x192, XCD-chunk swizzle (round 7 validated,
// unchanged).
// ---------------------------------------------------------------------------
__global__ __launch_bounds__(256, 3)
void gemm1_attn_kernel(const u16* __restrict__ xb, const u16* __restrict__ Wab,
                       const u16* __restrict__ VsT, u16* __restrict__ Hb)
{
    __shared__ u16 smem[16384];   // 32 KB: A dbuf 2x2048, B dbuf 2x6144 (u16)

    const int tid  = threadIdx.x;
    const int lane = tid & 63, wave = tid >> 6;
    const int quad = lane >> 4, l16 = lane & 15;
    const int wm = (wave & 1) * 32;          // row half (32 rows)
    const int wn = (wave >> 1) * 96;         // col half = one head

    const int p = blockIdx.x;                // [0,768)
    const int w = (p & 7) * 96 + (p >> 3);   // bijective XCD-chunk swizzle
    const int rowb = w / 6, colb = w % 6;    // A-panel-major
    const int m0 = rowb * 64, n0 = colb * 192;

    const int K = DIMC;
    const int NT = K / 32;                   // 24

    const int lrow = lane >> 2, lchunk = lane & 3;
    const u16* gA = xb  + (size_t)(m0 + wave * 16 + lrow) * K + lchunk * 8;
    const u16* gB = Wab + (size_t)(n0 + wave * 48 + lrow) * K + lchunk * 8;

    // As[buf] = smem + buf*2048 (64x32); Bs[buf] = smem + 4096 + buf*6144 (192x32)
#define STAGE(buf, kt_) do {                                                  \
        const int _k0 = (kt_) * 32;                                           \
        u16* _as = smem + (buf) * 2048 + wave * 512;                          \
        u16* _bs = smem + 4096 + (buf) * 6144 + wave * 1536;                  \
        async_load16(gA + _k0,          _as);                                 \
        async_load16(gB + _k0,          _bs);                                 \
        async_load16(gB + _k0 + 16 * K, _bs + 512);                          \
        async_load16(gB + _k0 + 32 * K, _bs + 1024);                         \
    } while (0)

#define COMPUTE(buf) do {                                                     \
        const u16* _as = smem + (buf) * 2048;                                 \
        const u16* _bs = smem + 4096 + (buf) * 6144;                          \
        short8 af[2], bfr[6];                                                 \
        _Pragma("unroll")                                                     \
        for (int t = 0; t < 2; ++t)                                           \
            af[t] = *(const short8*)&_as[(wm + t * 16 + l16) * 32 + quad * 8];\
        _Pragma("unroll")                                                     \
        for (int t = 0; t < 6; ++t)                                           \
            bfr[t] = *(const short8*)&_bs[(wn + t * 16 + l16) * 32 + quad * 8];\
        _Pragma("unroll")                                                     \
        for (int mt = 0; mt < 2; ++mt)                                        \
            _Pragma("unroll")                                                 \
            for (int ct = 0; ct < 6; ++ct)                                    \
                acc[mt][ct] = __builtin_amdgcn_mfma_f32_16x16x32_bf16(        \
                    af[mt], bfr[ct], acc[mt][ct], 0, 0, 0);                   \
    } while (0)

    floatx4 acc[2][6] = {};
    STAGE(0, 0);
    STAGE(1, 1);
#pragma unroll 2
    for (int kt = 0; kt < NT - 2; ++kt) {
        const int buf = kt & 1;
        __asm__ volatile("s_waitcnt vmcnt(4)" ::: "memory");
        __asm__ volatile("s_barrier" ::: "memory");
        COMPUTE(buf);
        __asm__ volatile("s_barrier" ::: "memory");
        STAGE(buf, kt + 2);
    }
    __asm__ volatile("s_waitcnt vmcnt(4)" ::: "memory");
    __asm__ volatile("s_barrier" ::: "memory");
    COMPUTE(0);                                  // kt = 22
    __asm__ volatile("s_waitcnt vmcnt(0)" ::: "memory");
    __asm__ volatile("s_barrier" ::: "memory");  // cross-wave staging complete
    COMPUTE(1);                                  // kt = 23
    __syncthreads();                             // staging LDS dead -> P overlay
#undef STAGE
#undef COMPUTE

    // ---------------- fused attention epilogue (wave-local) ----------------
    const int b = rowb >> 5;                     // m0 / 2048
    const int h = colb * 2 + (wave >> 1);
    const u16* vbase = VsT + ((size_t)b * HEADS + h) * 4096;

    short8 bV[4][2];
#pragma unroll
    for (int nt2 = 0; nt2 < 4; ++nt2)
#pragma unroll
        for (int kk = 0; kk < 2; ++kk)
            bV[nt2][kk] = *(const short8*)
                &vbase[(nt2 * 16 + l16) * 64 + kk * 32 + quad * 8];

    u16* Pw = smem + wave * 2304;                // 32 x 72 bf16, per wave
    const int srcl0 = quad * 16 + (l16 >> 1);    // b-col p>>1, frag-local
    const int srcl1 = srcl0 + 8;

    short8 ones;
#pragma unroll
    for (int j = 0; j < 8; ++j) ones[j] = (short)0x3F80;   // bf16 1.0

#pragma unroll
    for (int mt = 0; mt < 2; ++mt) {
        // scores s_p = a_p * b_{p/2}; cols of wave tile: [0,64)=a, [64,96)=b
#pragma unroll
        for (int nt = 0; nt < 4; ++nt) {
            const int src = (nt & 1) ? srcl1 : srcl0;
#pragma unroll
            for (int r = 0; r < 4; ++r) {
                float bsh = __shfl(acc[mt][4 + (nt >> 1)][r], src, 64);
                float e = __expf(acc[mt][nt][r] * bsh);
                Pw[(mt * 16 + quad * 4 + r) * 72 + nt * 16 + l16] = f2bf(e);
            }
        }
        // PV for this 16-row tile (wave-local)
        short8 a0 = *(const short8*)&Pw[(mt * 16 + l16) * 72 + quad * 8];
        short8 a1 = *(const short8*)&Pw[(mt * 16 + l16) * 72 + 32 + quad * 8];
        floatx4 sacc = {};
        sacc = __builtin_amdgcn_mfma_f32_16x16x32_bf16(a0, ones, sacc, 0, 0, 0);
        sacc = __builtin_amdgcn_mfma_f32_16x16x32_bf16(a1, ones, sacc, 0, 0, 0);
        floatx4 accO[4] = {};
#pragma unroll
        for (int nt2 = 0; nt2 < 4; ++nt2) {
            accO[nt2] = __builtin_amdgcn_mfma_f32_16x16x32_bf16(a0, bV[nt2][0], accO[nt2], 0, 0, 0);
            accO[nt2] = __builtin_amdgcn_mfma_f32_16x16x32_bf16(a1, bV[nt2][1], accO[nt2], 0, 0, 0);
        }
        float inv[4];
#pragma unroll
        for (int r = 0; r < 4; ++r) inv[r] = 1.0f / (32.0f * sacc[r]);
#pragma unroll
        for (int nt2 = 0; nt2 < 4; ++nt2)
#pragma unroll
            for (int rr = 0; rr < 4; ++rr) {
                const size_t row = (size_t)(m0 + wm + mt * 16 + quad * 4 + rr);
                Hb[row * DIMC + h * 64 + nt2 * 16 + l16] =
                    f2bf(accO[nt2][rr] * inv[rr]);
            }
    }
}

// ---------------------------------------------------------------------------
extern "C" void kernel_launch(void* const* d_in, const int* in_sizes, int n_in,
                              void* d_out, int out_size, void* d_ws, size_t ws_size,
                              hipStream_t stream)
{
    const float* x  = (const float*)d_in[0];
    const float* Wa = (const float*)d_in[1];
    const float* Wb = (const float*)d_in[2];
    const float* Wv = (const float*)d_in[3];
    const float* Wp = (const float*)d_in[4];
    const float* bp = (const float*)d_in[5];
    float* out = (float*)d_out;

    char* ws = (char*)d_ws;
    u16*   xb    = (u16*)ws;   ws += (size_t)MROWS * DIMC * 2;   // 12.6 MB
    u16*   Wtcat = (u16*)ws;   ws += (size_t)NCAT * DIMC * 2;    // 2.9 MB
    u16*   Wpt   = (u16*)ws;   ws += (size_t)DIMC * DIMC * 2;    // 1.2 MB
    u16*   xs    = (u16*)ws;   ws += (size_t)256 * DIMC * 2;     // 0.4 MB
    u16*   VsT   = (u16*)ws;   ws += (size_t)48 * 4096 * 2;      // 0.4 MB
    u16*   Hb    = (u16*)ws;                                     // 12.6 MB

    dim3 blk(256);

    prep_kernel<<<dim3(760), blk, 0, stream>>>(x, Wa, Wb, Wv, Wp,
                                               xb, Wtcat, Wpt, xs);

    vs_kernel<<<dim3(96), blk, 0, stream>>>(xs, Wtcat + (size_t)NAB * DIMC, VsT);

    gemm1_attn_kernel<<<dim3(768), blk, 0, stream>>>(xb, Wtcat, VsT, Hb);

    gemm_bf16_kernel<false><<<dim3(384), blk, 0, stream>>>(
        Hb, Wpt, bp, out, DIMC, DIMC, 6);
}